// Round 1
// baseline (154.586 us; speedup 1.0000x reference)
//
#include <hip/hip_runtime.h>
#include <math.h>

#define NPATCH 196
#define PI_F 3.14159265358979323846f

// order-preserving float<->uint encoding (works for all floats; inputs are >=0 anyway)
__device__ __forceinline__ unsigned fkey(float f) {
  unsigned u = __float_as_uint(f);
  return u ^ ((unsigned)((int)u >> 31) | 0x80000000u);
}
__device__ __forceinline__ float funkey(unsigned k) {
  unsigned u = (k & 0x80000000u) ? (k ^ 0x80000000u) : ~k;
  return __uint_as_float(u);
}

// Kernel 1: per-patch-position min/max over the whole batch.
// grid = B/imgs_per_block blocks, 256 threads. Coalesced reads; LDS atomics;
// device-scope global atomics into ws (pre-initialized by hipMemsetAsync).
__global__ void __launch_bounds__(256) minmax_kernel(const float* __restrict__ x,
                                                     unsigned* __restrict__ mn,
                                                     unsigned* __restrict__ mx,
                                                     int imgs_per_block) {
  __shared__ unsigned smin[NPATCH], smax[NPATCH];
  for (int t = threadIdx.x; t < NPATCH; t += 256) { smin[t] = 0xFFFFFFFFu; smax[t] = 0u; }
  __syncthreads();
  const int per = imgs_per_block * 784;
  const size_t base = (size_t)blockIdx.x * (size_t)per;
  for (int idx = threadIdx.x; idx < per; idx += 256) {
    float v = x[base + idx];
    int pix = idx % 784;
    int rr = pix / 28;
    int cc = pix - rr * 28;
    int p = (rr >> 1) * 14 + (cc >> 1);
    unsigned key = fkey(v);
    atomicMin(&smin[p], key);
    atomicMax(&smax[p], key);
  }
  __syncthreads();
  for (int t = threadIdx.x; t < NPATCH; t += 256) {
    atomicMin(&mn[t], smin[t]);
    atomicMax(&mx[t], smax[t]);
  }
}

// Kernel 2: one block per image. Full fusion: angles -> circuit -> scrambled
// feature vector -> residual -> 784x10 classifier -> log_softmax.
__global__ void __launch_bounds__(256) quanv_kernel(
    const float* __restrict__ x, const float* __restrict__ params,
    const float* __restrict__ res_w, const float* __restrict__ cls_w,
    const float* __restrict__ cls_b, const unsigned* __restrict__ mnk,
    const unsigned* __restrict__ mxk, float* __restrict__ out) {
  __shared__ float img[784];
  __shared__ float ovec[784];   // out.reshape(B,784) flat order
  __shared__ float cp[12], sp[12];
  __shared__ float wred[4][10];
  __shared__ float lg[10];
  const int tid = threadIdx.x;
  const int b = blockIdx.x;

  for (int t = tid; t < 784; t += 256) img[t] = x[(size_t)b * 784 + t];
  if (tid < 12) {
    float half = 0.5f * params[tid];   // params[l,q,0] flat l*4+q
    __sincosf(half, &sp[tid], &cp[tid]);
  }
  __syncthreads();

  if (tid < NPATCH) {
    const int p = tid;
    const int pi = p / 14, pj = p - pi * 14;
    const float mnv = funkey(mnk[p]);
    const float mxv = funkey(mxk[p]);
    const float sc = PI_F / (mxv - mnv + 1e-8f);
    // patch element order: (r,c),(r,c+1),(r+1,c),(r+1,c+1) -> qubits 0..3
    float av[4];
    av[0] = img[(2 * pi) * 28 + 2 * pj];
    av[1] = img[(2 * pi) * 28 + 2 * pj + 1];
    av[2] = img[(2 * pi + 1) * 28 + 2 * pj];
    av[3] = img[(2 * pi + 1) * 28 + 2 * pj + 1];
    float cc4[4], ss4[4];
#pragma unroll
    for (int q = 0; q < 4; ++q) {
      float half = 0.5f * (av[q] - mnv) * sc;   // 0.5 * angle
      __sincosf(half, &ss4[q], &cc4[q]);
    }
    // product state after the 4 input RYs; flat idx bit (8>>q) = wire q
    float st[16];
#pragma unroll
    for (int idx = 0; idx < 16; ++idx) {
      st[idx] = ((idx & 8) ? ss4[0] : cc4[0]) * ((idx & 4) ? ss4[1] : cc4[1]) *
                ((idx & 2) ? ss4[2] : cc4[2]) * ((idx & 1) ? ss4[3] : cc4[3]);
    }
    // 3 variational layers: RY on each wire, then CNOT chain (0,1)(1,2)(2,3)
#pragma unroll
    for (int l = 0; l < 3; ++l) {
#pragma unroll
      for (int q = 0; q < 4; ++q) {
        const float cq = cp[l * 4 + q], sq = sp[l * 4 + q];
        const int m = 8 >> q;
#pragma unroll
        for (int idx = 0; idx < 16; ++idx) {
          if (idx & m) continue;
          float v0 = st[idx], v1 = st[idx | m];
          st[idx] = cq * v0 - sq * v1;
          st[idx | m] = sq * v0 + cq * v1;
        }
      }
#pragma unroll
      for (int q = 0; q < 3; ++q) {
        const int mc = 8 >> q, mt = 4 >> q;
#pragma unroll
        for (int idx = 0; idx < 16; ++idx) {
          if ((idx & mc) && !(idx & mt)) {
            float t0 = st[idx];
            st[idx] = st[idx | mt];
            st[idx | mt] = t0;
          }
        }
      }
    }
    // <Z_w> = sum_{bit_w=0} p - sum_{bit_w=1} p
    float z0 = 0.f, z1 = 0.f, z2 = 0.f, z3 = 0.f;
#pragma unroll
    for (int idx = 0; idx < 16; ++idx) {
      float pr = st[idx] * st[idx];
      z0 += (idx & 8) ? -pr : pr;
      z1 += (idx & 4) ? -pr : pr;
      z2 += (idx & 2) ? -pr : pr;
      z3 += (idx & 1) ? -pr : pr;
    }
    ovec[4 * p + 0] = z0;
    ovec[4 * p + 1] = z1;
    ovec[4 * p + 2] = z2;
    ovec[4 * p + 3] = z3;
  }
  __syncthreads();

  // residual: out[b,c,i,j] += img[b,2i,2j]*res_w[c]; flat t = c*196+i*14+j
  for (int t = tid; t < 784; t += 256) {
    int c = t / 196;
    int rem = t - c * 196;
    int i = rem / 14, j = rem - i * 14;
    ovec[t] += img[(2 * i) * 28 + 2 * j] * res_w[c];
  }
  __syncthreads();

  // classifier: logits[k] = cls_b[k] + dot(cls_w[k,:], ovec)
  float acc[10];
#pragma unroll
  for (int k = 0; k < 10; ++k) acc[k] = 0.f;
  for (int t = tid; t < 784; t += 256) {
    float v = ovec[t];
#pragma unroll
    for (int k = 0; k < 10; ++k) acc[k] += v * cls_w[k * 784 + t];
  }
#pragma unroll
  for (int k = 0; k < 10; ++k) {
    float a = acc[k];
#pragma unroll
    for (int off = 32; off > 0; off >>= 1) a += __shfl_down(a, off, 64);
    acc[k] = a;
  }
  const int lane = tid & 63, wave = tid >> 6;
  if (lane == 0) {
#pragma unroll
    for (int k = 0; k < 10; ++k) wred[wave][k] = acc[k];
  }
  __syncthreads();
  if (tid < 10) {
    float s = cls_b[tid];
#pragma unroll
    for (int w = 0; w < 4; ++w) s += wred[w][tid];
    lg[tid] = s;
  }
  __syncthreads();
  if (tid < 10) {
    float m = lg[0];
#pragma unroll
    for (int k = 1; k < 10; ++k) m = fmaxf(m, lg[k]);
    float ssum = 0.f;
#pragma unroll
    for (int k = 0; k < 10; ++k) ssum += __expf(lg[k] - m);
    out[(size_t)b * 10 + tid] = lg[tid] - m - __logf(ssum);
  }
}

extern "C" void kernel_launch(void* const* d_in, const int* in_sizes, int n_in,
                              void* d_out, int out_size, void* d_ws, size_t ws_size,
                              hipStream_t stream) {
  const float* x      = (const float*)d_in[0];
  const float* params = (const float*)d_in[1];
  const float* res_w  = (const float*)d_in[2];
  const float* cls_w  = (const float*)d_in[3];
  const float* cls_b  = (const float*)d_in[4];
  float* out = (float*)d_out;
  const int B = in_sizes[0] / 784;

  unsigned* mn = (unsigned*)d_ws;
  unsigned* mx = mn + NPATCH;
  // init reduction buffers (ws is poisoned 0xAA before every launch)
  hipMemsetAsync(mn, 0xFF, NPATCH * sizeof(unsigned), stream);  // uint max
  hipMemsetAsync(mx, 0x00, NPATCH * sizeof(unsigned), stream);  // uint min

  const int imgs_per_block = 32;
  const int nblk1 = (B + imgs_per_block - 1) / imgs_per_block;
  minmax_kernel<<<nblk1, 256, 0, stream>>>(x, mn, mx, imgs_per_block);
  quanv_kernel<<<B, 256, 0, stream>>>(x, params, res_w, cls_w, cls_b, mn, mx, out);
}

// Round 3
// 130.930 us; speedup vs baseline: 1.1807x; 1.1807x over previous
//
#include <hip/hip_runtime.h>
#include <math.h>

#define NP 196
#define PI_F 3.14159265358979323846f

// order-preserving float<->uint encoding (monotone: min of keys == key of min)
__device__ __forceinline__ unsigned fkey(float f) {
  unsigned u = __float_as_uint(f);
  return u ^ ((unsigned)((int)u >> 31) | 0x80000000u);
}
__device__ __forceinline__ float funkey(unsigned k) {
  unsigned u = (k & 0x80000000u) ? (k ^ 0x80000000u) : ~k;
  return __uint_as_float(u);
}

// ---------------------------------------------------------------------------
// K0: precompute U (16x16, the fixed 3-layer variational circuit as a matrix)
// and W2[k,p] = sum_c res_w[c]*cls_w[k, c*196+p] (residual folded into cls).
// ---------------------------------------------------------------------------
__global__ void __launch_bounds__(256) precompute_kernel(
    const float* __restrict__ params, const float* __restrict__ res_w,
    const float* __restrict__ cls_w, float* __restrict__ U,
    float* __restrict__ W2) {
  const int tid = threadIdx.x;
  if (tid < 16) {
    float cp[12], sp[12];
#pragma unroll
    for (int l = 0; l < 12; ++l) __sincosf(0.5f * params[l], &sp[l], &cp[l]);
    float st[16];
#pragma unroll
    for (int i = 0; i < 16; ++i) st[i] = 0.f;
    st[tid] = 1.f;  // basis vector e_j -> column j of U
#pragma unroll
    for (int l = 0; l < 3; ++l) {
#pragma unroll
      for (int q = 0; q < 4; ++q) {
        const float cq = cp[l * 4 + q], sq = sp[l * 4 + q];
        const int m = 8 >> q;
#pragma unroll
        for (int idx = 0; idx < 16; ++idx) {
          if (idx & m) continue;
          float v0 = st[idx], v1 = st[idx | m];
          st[idx] = cq * v0 - sq * v1;
          st[idx | m] = sq * v0 + cq * v1;
        }
      }
#pragma unroll
      for (int q = 0; q < 3; ++q) {
        const int mc = 8 >> q, mt = 4 >> q;
#pragma unroll
        for (int idx = 0; idx < 16; ++idx) {
          if ((idx & mc) && !(idx & mt)) {
            float t0 = st[idx];
            st[idx] = st[idx | mt];
            st[idx | mt] = t0;
          }
        }
      }
    }
#pragma unroll
    for (int i = 0; i < 16; ++i) U[i * 16 + tid] = st[i];
  }
  for (int t = tid; t < 10 * NP; t += 256) {
    int k = t / NP, p = t - k * NP;
    float s = 0.f;
#pragma unroll
    for (int c = 0; c < 4; ++c) s += res_w[c] * cls_w[k * 784 + c * NP + p];
    W2[t] = s;
  }
}

// ---------------------------------------------------------------------------
// K1: per-patch-position min/max over the batch. No atomics in the hot loop:
// thread t<392 owns one (row, col-pair) position, register-reduces over
// `imgs` images with coalesced float2 loads; one global atomic per patch/blk.
// ---------------------------------------------------------------------------
__global__ void __launch_bounds__(512) minmax_kernel(
    const float* __restrict__ x, unsigned* __restrict__ mn,
    unsigned* __restrict__ mx, int imgs, int B) {
  __shared__ unsigned skmin[392], skmax[392];
  const int t = threadIdx.x;
  const int img0 = blockIdx.x * imgs;
  if (t < 392) {
    const int r = t / 14, j = t - r * 14;
    const float* base = x + (size_t)img0 * 784 + r * 28 + 2 * j;
    float lmn = 3.4e38f, lmx = -3.4e38f;
    const int nimg = (img0 + imgs <= B) ? imgs : (B - img0);
#pragma unroll 4
    for (int m = 0; m < nimg; ++m) {
      float2 v = *(const float2*)(base + (size_t)m * 784);
      lmn = fminf(lmn, fminf(v.x, v.y));
      lmx = fmaxf(lmx, fmaxf(v.x, v.y));
    }
    skmin[t] = fkey(lmn);
    skmax[t] = fkey(lmx);
  }
  __syncthreads();
  if (t < NP) {
    const int i = t / 14, j = t - i * 14;
    const int f0 = (2 * i) * 14 + j, f1 = f0 + 14;
    unsigned kmn = skmin[f0] < skmin[f1] ? skmin[f0] : skmin[f1];
    unsigned kmx = skmax[f0] > skmax[f1] ? skmax[f0] : skmax[f1];
    atomicMin(&mn[t], kmn);
    atomicMax(&mx[t], kmx);
  }
}

// ---------------------------------------------------------------------------
// K2: one thread per circuit (B*196 total). Product state + U matvec
// (U via wave-uniform scalar loads) + signed squares -> 4 <Z> values.
// Output layout: gmeas[b*784 + p*4 + w]  (== reference meas flat order),
// i.e. one float4 at index g = b*196+p  -> fully coalesced store.
// ---------------------------------------------------------------------------
__global__ void __launch_bounds__(256) circuit_kernel(
    const float* __restrict__ x, const unsigned* __restrict__ mnk,
    const unsigned* __restrict__ mxk, const float* __restrict__ U,
    float4* __restrict__ gmeas, int G) {
  const int g = blockIdx.x * 256 + threadIdx.x;
  if (g >= G) return;
  const int b = g / NP;
  const int p = g - b * NP;
  const int i = p / 14, j = p - i * 14;

  const float* px = x + (size_t)b * 784 + (2 * i) * 28 + 2 * j;
  const float2 r0 = *(const float2*)px;
  const float2 r1 = *(const float2*)(px + 28);

  const float mnv = funkey(mnk[p]);
  const float mxv = funkey(mxk[p]);
  const float sc = (0.5f * PI_F) / (mxv - mnv + 1e-8f);  // half-angle scale

  float cc[4], ss[4];
  __sincosf((r0.x - mnv) * sc, &ss[0], &cc[0]);
  __sincosf((r0.y - mnv) * sc, &ss[1], &cc[1]);
  __sincosf((r1.x - mnv) * sc, &ss[2], &cc[2]);
  __sincosf((r1.y - mnv) * sc, &ss[3], &cc[3]);

  // product state; index bit (8>>q) = wire q
  float st0[16];
  {
    const float A[4] = {cc[0] * cc[1], cc[0] * ss[1], ss[0] * cc[1], ss[0] * ss[1]};
    const float Bq[4] = {cc[2] * cc[3], cc[2] * ss[3], ss[2] * cc[3], ss[2] * ss[3]};
#pragma unroll
    for (int idx = 0; idx < 16; ++idx) st0[idx] = A[idx >> 2] * Bq[idx & 3];
  }

  float z0 = 0.f, z1 = 0.f, z2 = 0.f, z3 = 0.f;
#pragma unroll
  for (int i2 = 0; i2 < 16; ++i2) {
    float f = 0.f;
#pragma unroll
    for (int jx = 0; jx < 16; ++jx) f = fmaf(U[i2 * 16 + jx], st0[jx], f);
    const float sq = f * f;
    z0 += (i2 & 8) ? -sq : sq;
    z1 += (i2 & 4) ? -sq : sq;
    z2 += (i2 & 2) ? -sq : sq;
    z3 += (i2 & 1) ? -sq : sq;
  }
  gmeas[g] = make_float4(z0, z1, z2, z3);
}

// ---------------------------------------------------------------------------
// K3: classifier + residual + log_softmax. One wave per image.
// ---------------------------------------------------------------------------
__global__ void __launch_bounds__(256) cls_kernel(
    const float* __restrict__ gmeas, const float* __restrict__ x,
    const float* __restrict__ W2, const float* __restrict__ cls_w,
    const float* __restrict__ cls_b, float* __restrict__ out, int B) {
  const int wv = (blockIdx.x * 256 + threadIdx.x) >> 6;
  const int lane = threadIdx.x & 63;
  if (wv >= B) return;  // wave-uniform
  const float* mrow = gmeas + (size_t)wv * 784;
  const float* xrow = x + (size_t)wv * 784;

  float acc[10];
#pragma unroll
  for (int k = 0; k < 10; ++k) acc[k] = 0.f;

  for (int t = lane; t < 784; t += 64) {
    const float v = mrow[t];
#pragma unroll
    for (int k = 0; k < 10; ++k) acc[k] = fmaf(v, cls_w[k * 784 + t], acc[k]);
  }
  for (int p = lane; p < NP; p += 64) {
    const int i = p / 14, j = p - i * 14;
    const float v = xrow[(2 * i) * 28 + 2 * j];
#pragma unroll
    for (int k = 0; k < 10; ++k) acc[k] = fmaf(v, W2[k * NP + p], acc[k]);
  }
#pragma unroll
  for (int k = 0; k < 10; ++k) {
    float a = acc[k];
#pragma unroll
    for (int off = 32; off > 0; off >>= 1) a += __shfl_down(a, off, 64);
    acc[k] = a;
  }
  if (lane == 0) {
    float lg[10];
#pragma unroll
    for (int k = 0; k < 10; ++k) lg[k] = acc[k] + cls_b[k];
    float m = lg[0];
#pragma unroll
    for (int k = 1; k < 10; ++k) m = fmaxf(m, lg[k]);
    float s = 0.f;
#pragma unroll
    for (int k = 0; k < 10; ++k) s += __expf(lg[k] - m);
    const float lse = m + __logf(s);
#pragma unroll
    for (int k = 0; k < 10; ++k) out[(size_t)wv * 10 + k] = lg[k] - lse;
  }
}

extern "C" void kernel_launch(void* const* d_in, const int* in_sizes, int n_in,
                              void* d_out, int out_size, void* d_ws, size_t ws_size,
                              hipStream_t stream) {
  const float* x      = (const float*)d_in[0];
  const float* params = (const float*)d_in[1];
  const float* res_w  = (const float*)d_in[2];
  const float* cls_w  = (const float*)d_in[3];
  const float* cls_b  = (const float*)d_in[4];
  float* out = (float*)d_out;
  const int B = in_sizes[0] / 784;

  // ws layout: mn[196] u32 | mx[196] u32 | U[256] f32 | W2[1960] f32 | gmeas[B*784] f32
  unsigned* mn = (unsigned*)d_ws;
  unsigned* mx = mn + NP;
  float* U  = (float*)(mx + NP);
  float* W2 = U + 256;
  float* gmeas = W2 + 10 * NP;  // float offset 2608 -> 16B aligned

  hipMemsetAsync(mn, 0xFF, NP * sizeof(unsigned), stream);  // uint max
  hipMemsetAsync(mx, 0x00, NP * sizeof(unsigned), stream);  // uint min

  precompute_kernel<<<1, 256, 0, stream>>>(params, res_w, cls_w, U, W2);

  const int imgs = 16;
  const int nblk1 = (B + imgs - 1) / imgs;
  minmax_kernel<<<nblk1, 512, 0, stream>>>(x, mn, mx, imgs, B);

  const int G = B * NP;
  circuit_kernel<<<(G + 255) / 256, 256, 0, stream>>>(x, mn, mx, U, (float4*)gmeas, G);

  cls_kernel<<<(B * 64 + 255) / 256, 256, 0, stream>>>(gmeas, x, W2, cls_w, cls_b, out, B);
}